// Round 13
// baseline (201.750 us; speedup 1.0000x reference)
//
#include <hip/hip_runtime.h>
#include <cstddef>

#define N_NODES 16384
#define N_EDGES 131072
#define BGR 256
#define NF 64
#define EF 32
#define GF 16

typedef __attribute__((ext_vector_type(8))) short bf16x8;
typedef __attribute__((ext_vector_type(4))) float f32x4;

#define MFMA16(a, b, c) __builtin_amdgcn_mfma_f32_16x16x32_bf16((a), (b), (c), 0, 0, 0)
__device__ const f32x4 ZERO4 = {0.f, 0.f, 0.f, 0.f};

__device__ inline unsigned short f2bf(float f) {
    return (unsigned short)((__builtin_bit_cast(unsigned, f) + 0x8000u) >> 16);
}
__device__ inline float bfs(unsigned short x) {
    return __builtin_bit_cast(float, (unsigned)x << 16);
}

__device__ inline bf16x8 pack8(float4 f0, float4 f1) {
    bf16x8 a;
    a[0] = (short)f2bf(f0.x); a[1] = (short)f2bf(f0.y);
    a[2] = (short)f2bf(f0.z); a[3] = (short)f2bf(f0.w);
    a[4] = (short)f2bf(f1.x); a[5] = (short)f2bf(f1.y);
    a[6] = (short)f2bf(f1.z); a[7] = (short)f2bf(f1.w);
    return a;
}

// --------------------------------------------------------------------- prep
extern "C" __global__ void __launch_bounds__(256)
k_prep(const float* __restrict__ We1, const float* __restrict__ We2,
       const float* __restrict__ Wn1, const float* __restrict__ Win1,
       const float* __restrict__ Wn2, const float* __restrict__ Win2,
       unsigned short* We1p, unsigned short* We2p, unsigned short* Wn1p,
       unsigned short* Win1p, unsigned short* Wn2p, unsigned short* Win2p,
       const float* __restrict__ gf,
       const float* __restrict__ Weg2, const float* __restrict__ be2,
       const float* __restrict__ Wng2, const float* __restrict__ bn2,
       float* __restrict__ gproj_e, float* __restrict__ gproj_n,
       const int* __restrict__ receivers, int* cntR,
       const int* __restrict__ node_graph, const int* __restrict__ edge_graph,
       int* offN, int* offE)
{
    const int bid = blockIdx.x, tid = threadIdx.x;
    if (bid < 84) {
        const int fi = bid * 4 + (tid >> 6), l = tid & 63;
        const float* W; unsigned short* P; int N, t;
        if      (fi < 16)  { W = We1;  P = We1p;  N = 256; t = fi;       }
        else if (fi < 80)  { W = We2;  P = We2p;  N = 128; t = fi - 16;  }
        else if (fi < 112) { W = Wn1;  P = Wn1p;  N = 256; t = fi - 80;  }
        else if (fi < 240) { W = Win1; P = Win1p; N = 256; t = fi - 112; }
        else if (fi < 304) { W = Wn2;  P = Wn2p;  N = 128; t = fi - 240; }
        else               { W = Win2; P = Win2p; N = 128; t = fi - 304; }
        const int NT = N / 16;
        const int kt = t / NT, nt = t % NT;
        const int k0 = kt * 32 + (l >> 4) * 8;
        const int col = nt * 16 + (l & 15);
        unsigned short* dst = P + ((size_t)t * 64 + l) * 8;
        #pragma unroll
        for (int j = 0; j < 8; ++j) dst[j] = f2bf(W[(size_t)(k0 + j) * N + col]);
    } else if (bid < 212) {
        const int b = (bid - 84) * 2 + (tid >> 7), t = tid & 127;
        float ge = be2[t], gn = bn2[t];
        #pragma unroll
        for (int j = 0; j < GF; ++j) {
            const float g = gf[b * GF + j];
            ge = fmaf(g, Weg2[j * 128 + t], ge);
            gn = fmaf(g, Wng2[j * 128 + t], gn);
        }
        gproj_e[b * 128 + t] = ge;
        gproj_n[b * 128 + t] = gn;
    } else if (bid < 724) {
        const int i = (bid - 212) * 256 + tid;
        atomicAdd(&cntR[receivers[i]], 1);
    } else {
        const int g = tid;
        const int* arr = (bid == 725) ? edge_graph : node_graph;
        int* dst       = (bid == 725) ? offE       : offN;
        const int len  = (bid == 725) ? N_EDGES    : N_NODES;
        int lo = 0, hi = len;
        while (lo < hi) {
            const int mid = (lo + hi) >> 1;
            if (arr[mid] < g) lo = mid + 1; else hi = mid;
        }
        dst[g] = lo;
        if (g == 0) dst[256] = len;
    }
}

// ---------------------------------------------------------- parallel scan
extern "C" __global__ void __launch_bounds__(256)
k_scanA(const int* __restrict__ cntR, int* __restrict__ offR, int* __restrict__ bsum)
{
    __shared__ int sm[256];
    const int b = blockIdx.x, t = threadIdx.x;
    const int4 v = *(const int4*)(cntR + b * 1024 + t * 4);
    const int s = v.x + v.y + v.z + v.w;
    sm[t] = s; __syncthreads();
    for (int o = 1; o < 256; o <<= 1) {
        int x = (t >= o) ? sm[t - o] : 0;
        __syncthreads(); sm[t] += x; __syncthreads();
    }
    const int excl = sm[t] - s;
    int4 o;
    o.x = excl; o.y = excl + v.x; o.z = o.y + v.y; o.w = o.z + v.z;
    *(int4*)(offR + b * 1024 + t * 4) = o;
    if (t == 255) bsum[b] = sm[255];
}

extern "C" __global__ void __launch_bounds__(256)
k_scanB(int* __restrict__ offR, const int* __restrict__ bsum)
{
    const int i = blockIdx.x * 256 + threadIdx.x;
    if (i > 16384) return;
    const int g = i >> 10;
    int pre = 0;
    for (int k = 0; k < g; ++k) pre += bsum[k];
    offR[i] = (i < 16384 ? offR[i] : 0) + pre;
}

extern "C" __global__ void __launch_bounds__(256)
k_scatter(const int* __restrict__ receivers, const int* __restrict__ offR,
          int* curR, int* perm)
{
    const int i = blockIdx.x * 256 + threadIdx.x;
    if (i < N_EDGES) {
        const int r = receivers[i];
        const int pos = offR[r] + atomicAdd(&curR[r], 1);
        perm[pos] = i;
    }
}

// ---------------------------------------------------------------- edge block
// PERM (receiver-sorted) order, 64 edges/block, 4 waves tiling N.
// e1 MFMA -> LDS (for e2) + REGISTER segment-sums -> mean1g / pfirst1,plast1.
// e2 MFMA -> LDS (for e2g dump) + REGISTER segment-sums -> mean2g / p*2.
// No e1 in HBM at all.
extern "C" __global__ void __launch_bounds__(256)
k_edge(const float* __restrict__ edge_feats,
       const int* __restrict__ perm,
       const int* __restrict__ receivers,
       const int* __restrict__ edge_graph,
       const unsigned short* __restrict__ We1p,
       const unsigned short* __restrict__ We2p,
       const float* __restrict__ be1,
       const float* __restrict__ gproj_e,
       const int* __restrict__ offR,
       unsigned short* __restrict__ mean1g,
       unsigned short* __restrict__ mean2g,
       float* __restrict__ pfirst1, float* __restrict__ plast1,
       float* __restrict__ pfirst2, float* __restrict__ plast2,
       unsigned short* __restrict__ e2g)
{
    __shared__ __align__(16) unsigned short e1s[64 * 256];   // 32 KB, swizzled
    __shared__ int nidL[64], eidL[64], segS[64], segE[64];
    const int tid = threadIdx.x;
    const int w = tid >> 6, l = tid & 63;
    const int lr = l & 15, lq = l >> 4;
    const int blk = blockIdx.x;
    const int e0 = blk * 64;
    char* B = (char*)e1s;

    if (tid < 64) {
        const int pe = perm[e0 + tid];
        eidL[tid] = pe;
        nidL[tid] = receivers[pe];
    }
    __syncthreads();

    // segment masks (identical across waves) — R11-verified bookkeeping
    const int myn = nidL[l];
    const bool bound = (l == 0) || (nidL[l - 1] != myn);
    const bool endb  = (l == 63) || (nidL[l + 1] != myn);
    const unsigned long long mask  = __ballot(bound);
    const unsigned long long emask = __ballot(endb);
    const int nseg = __popcll(mask);
    if (tid < 64) {
        if (bound) segS[__popcll(mask  & ((1ull << tid) - 1ull))] = tid;
        if (endb)  segE[__popcll(emask & ((1ull << tid) - 1ull))] = tid;
    }
    const bool fS = (offR[nidL[0]] == e0);
    const bool lE = (offR[nidL[63] + 1] == e0 + 64);
    __syncthreads();   // segS/segE visible to all waves

    int eidA[4], egC[4][4];
    #pragma unroll
    for (int g = 0; g < 4; ++g) eidA[g] = eidL[g * 16 + lr];
    #pragma unroll
    for (int g = 0; g < 4; ++g)
        #pragma unroll
        for (int i = 0; i < 4; ++i)
            egC[g][i] = edge_graph[eidL[g * 16 + lq * 4 + i]];

    // ---- e1: M=64 (A shared), wave owns nt = w*4..w*4+3 ----
    bf16x8 a[4];
    #pragma unroll
    for (int g = 0; g < 4; ++g) {
        const float* s = edge_feats + (size_t)eidA[g] * EF + lq * 8;
        a[g] = pack8(*(const float4*)s, *(const float4*)(s + 4));
    }
    #pragma unroll
    for (int j = 0; j < 4; ++j) {
        const int nt = w * 4 + j;
        bf16x8 bfr = *(const bf16x8*)(We1p + ((size_t)nt * 64 + l) * 8);
        const int col = nt * 16 + lr;
        const float bias = be1[col];
        float v[4][4];
        #pragma unroll
        for (int g = 0; g < 4; ++g) {
            f32x4 c = MFMA16(a[g], bfr, ZERO4);
            #pragma unroll
            for (int i = 0; i < 4; ++i) {
                const int row = g * 16 + lq * 4 + i;
                v[g][i] = fmaxf(c[i] + bias, 0.f);
                *(unsigned short*)(B + row * 512 + ((col * 2) ^ ((row & 7) << 4))) = f2bf(v[g][i]);
            }
        }
        // register segment-sums for this col
        for (int s = 0; s < nseg; ++s) {
            const int as = segS[s], bs = segE[s];
            float sum = 0.f;
            #pragma unroll
            for (int g = 0; g < 4; ++g)
                #pragma unroll
                for (int i = 0; i < 4; ++i) {
                    const int row = g * 16 + lq * 4 + i;
                    sum += ((unsigned)(row - as) <= (unsigned)(bs - as)) ? v[g][i] : 0.f;
                }
            sum += __shfl_xor(sum, 16);
            sum += __shfl_xor(sum, 32);
            if (lq == 0) {
                const int n = nidL[as];
                if ((as > 0 || fS) && (bs < 63 || lE))
                    mean1g[(size_t)n * 256 + col] = f2bf(sum / (float)(bs - as + 1));
                else if (as == 0)
                    pfirst1[(size_t)blk * 256 + col] = sum;
                else
                    plast1[(size_t)blk * 256 + col] = sum;
            }
        }
    }
    __syncthreads();

    // ---- e2 GEMM: K=256 from LDS, wave owns nt = w*2, w*2+1 ----
    f32x4 acc[4][2];
    #pragma unroll
    for (int g = 0; g < 4; ++g) { acc[g][0] = ZERO4; acc[g][1] = ZERO4; }
    #pragma unroll
    for (int kt = 0; kt < 8; ++kt) {
        bf16x8 pA[4];
        #pragma unroll
        for (int g = 0; g < 4; ++g) {
            const int row = g * 16 + lr;
            pA[g] = *(const bf16x8*)(B + row * 512 + ((kt * 64 + lq * 16) ^ ((lr & 7) << 4)));
        }
        #pragma unroll
        for (int j = 0; j < 2; ++j) {
            const int nt = w * 2 + j;
            bf16x8 bfr = *(const bf16x8*)(We2p + ((size_t)(kt * 8 + nt) * 64 + l) * 8);
            #pragma unroll
            for (int g = 0; g < 4; ++g) acc[g][j] = MFMA16(pA[g], bfr, acc[g][j]);
        }
    }
    __syncthreads();   // all e1 LDS reads done before overwrite

    #pragma unroll
    for (int j = 0; j < 2; ++j) {
        const int nt = w * 2 + j, col = nt * 16 + lr;
        float v[4][4];
        #pragma unroll
        for (int g = 0; g < 4; ++g)
            #pragma unroll
            for (int i = 0; i < 4; ++i) {
                const int row = g * 16 + lq * 4 + i;
                v[g][i] = fmaxf(acc[g][j][i] + gproj_e[(size_t)egC[g][i] * 128 + col], 0.f);
                *(unsigned short*)(B + row * 512 + ((col * 2) ^ ((row & 7) << 4))) = f2bf(v[g][i]);
            }
        for (int s = 0; s < nseg; ++s) {
            const int as = segS[s], bs = segE[s];
            float sum = 0.f;
            #pragma unroll
            for (int g = 0; g < 4; ++g)
                #pragma unroll
                for (int i = 0; i < 4; ++i) {
                    const int row = g * 16 + lq * 4 + i;
                    sum += ((unsigned)(row - as) <= (unsigned)(bs - as)) ? v[g][i] : 0.f;
                }
            sum += __shfl_xor(sum, 16);
            sum += __shfl_xor(sum, 32);
            if (lq == 0) {
                const int n = nidL[as];
                if ((as > 0 || fS) && (bs < 63 || lE))
                    mean2g[(size_t)n * 128 + col] = f2bf(sum / (float)(bs - as + 1));
                else if (as == 0)
                    pfirst2[(size_t)blk * 128 + col] = sum;
                else
                    plast2[(size_t)blk * 128 + col] = sum;
            }
        }
    }
    __syncthreads();

    // ---- e2 dump in ORIGINAL order (scatter by eid, 256B granules) ----
    #pragma unroll
    for (int it = 0; it < 4; ++it) {
        const int flat = it * 4096 + tid * 16;
        const int row = flat >> 8, colb = flat & 255;
        bf16x8 v = *(const bf16x8*)(B + row * 512 + (colb ^ ((row & 7) << 4)));
        *(bf16x8*)(e2g + (size_t)eidL[row] * 128 + (colb >> 1)) = v;
    }
}

// -------------------------------------------- fused finish-mean + node block
extern "C" __global__ void __launch_bounds__(256)
k_nodeagg(const float* __restrict__ node_feats,
          const int* __restrict__ node_graph,
          const int* __restrict__ offR,
          const unsigned short* __restrict__ mean1g,
          const unsigned short* __restrict__ mean2g,
          const float* __restrict__ pfirst1, const float* __restrict__ plast1,
          const float* __restrict__ pfirst2, const float* __restrict__ plast2,
          const unsigned short* __restrict__ Wn1p,
          const unsigned short* __restrict__ Win1p,
          const unsigned short* __restrict__ Wn2p,
          const unsigned short* __restrict__ Win2p,
          const float* __restrict__ bn1,
          const float* __restrict__ gproj_n,
          unsigned short* __restrict__ n2g)
{
    __shared__ __align__(16) unsigned short m1s[16 * 256];   // 8 KB
    __shared__ __align__(16) unsigned short m2s[16 * 128];   // 4 KB (reused for n2)
    __shared__ __align__(16) unsigned short n1s[16 * 256];   // 8 KB
    __shared__ int offL[17];
    const int tid = threadIdx.x;
    const int w = tid >> 6, l = tid & 63;
    const int lr = l & 15, lq = l >> 4;
    const int n0 = blockIdx.x * 16;
    char* M1 = (char*)m1s; char* M2 = (char*)m2s; char* N1 = (char*)n1s;

    if (tid < 17) offL[tid] = offR[n0 + tid];
    __syncthreads();

    // ---- phase A: assemble means (R11-verified logic) ----
    #pragma unroll 1
    for (int rn = 0; rn < 16; ++rn) {
        const int c0 = offL[rn], c1 = offL[rn + 1];
        unsigned short u = 0;
        if (c1 > c0) {
            const int B0 = c0 >> 6, B1 = (c1 - 1) >> 6;
            if (B0 == B1) {
                u = mean1g[(size_t)(n0 + rn) * 256 + tid];
            } else {
                float sum = (c0 == (B0 << 6)) ? pfirst1[(size_t)B0 * 256 + tid]
                                              : plast1[(size_t)B0 * 256 + tid];
                for (int Bb = B0 + 1; Bb <= B1; ++Bb)
                    sum += pfirst1[(size_t)Bb * 256 + tid];
                u = f2bf(sum / (float)(c1 - c0));
            }
        }
        *(unsigned short*)(M1 + rn * 512 + ((tid * 2) ^ ((rn & 7) << 4))) = u;
    }
    if (tid < 128) {
        #pragma unroll 1
        for (int rn = 0; rn < 16; ++rn) {
            const int c0 = offL[rn], c1 = offL[rn + 1];
            unsigned short u = 0;
            if (c1 > c0) {
                const int B0 = c0 >> 6, B1 = (c1 - 1) >> 6;
                if (B0 == B1) {
                    u = mean2g[(size_t)(n0 + rn) * 128 + tid];
                } else {
                    float sum = (c0 == (B0 << 6)) ? pfirst2[(size_t)B0 * 128 + tid]
                                                  : plast2[(size_t)B0 * 128 + tid];
                    for (int Bb = B0 + 1; Bb <= B1; ++Bb)
                        sum += pfirst2[(size_t)Bb * 128 + tid];
                    u = f2bf(sum / (float)(c1 - c0));
                }
            }
            *(unsigned short*)(M2 + rn * 256 + ((tid * 2) ^ ((rn & 7) << 4))) = u;
        }
    }
    __syncthreads();

    // ---- phase B: n1 (M=16, K=64+256), wave owns nt = w*4..w*4+3 ----
    bf16x8 A1[10];
    #pragma unroll
    for (int kt = 0; kt < 2; ++kt) {
        const float* s = node_feats + (size_t)(n0 + lr) * NF + kt * 32 + lq * 8;
        A1[kt] = pack8(*(const float4*)s, *(const float4*)(s + 4));
    }
    #pragma unroll
    for (int kt = 0; kt < 8; ++kt)
        A1[2 + kt] = *(const bf16x8*)(M1 + lr * 512 + ((kt * 64 + lq * 16) ^ ((lr & 7) << 4)));
    #pragma unroll
    for (int j = 0; j < 4; ++j) {
        const int nt = w * 4 + j, col = nt * 16 + lr;
        f32x4 c = ZERO4;
        #pragma unroll
        for (int kt = 0; kt < 2; ++kt)
            c = MFMA16(A1[kt], *(const bf16x8*)(Wn1p + ((size_t)(kt * 16 + nt) * 64 + l) * 8), c);
        #pragma unroll
        for (int kt = 0; kt < 8; ++kt)
            c = MFMA16(A1[2 + kt], *(const bf16x8*)(Win1p + ((size_t)(kt * 16 + nt) * 64 + l) * 8), c);
        const float bias = bn1[col];
        #pragma unroll
        for (int i = 0; i < 4; ++i) {
            const int row = lq * 4 + i;
            const float v = fmaxf(c[i] + bias, 0.f);
            *(unsigned short*)(N1 + row * 512 + ((col * 2) ^ ((row & 7) << 4))) = f2bf(v);
        }
    }
    __syncthreads();

    // ---- phase C: n2 (M=16, K=256+128), wave owns nt = w*2, w*2+1 ----
    int ngv[4];
    #pragma unroll
    for (int i = 0; i < 4; ++i) ngv[i] = node_graph[n0 + lq * 4 + i];
    f32x4 acc[2];
    acc[0] = ZERO4; acc[1] = ZERO4;
    #pragma unroll
    for (int kt = 0; kt < 8; ++kt) {
        bf16x8 Aa = *(const bf16x8*)(N1 + lr * 512 + ((kt * 64 + lq * 16) ^ ((lr & 7) << 4)));
        #pragma unroll
        for (int j = 0; j < 2; ++j) {
            const int nt = w * 2 + j;
            acc[j] = MFMA16(Aa, *(const bf16x8*)(Wn2p + ((size_t)(kt * 8 + nt) * 64 + l) * 8), acc[j]);
        }
    }
    #pragma unroll
    for (int kt = 0; kt < 4; ++kt) {
        bf16x8 Aa = *(const bf16x8*)(M2 + lr * 256 + ((kt * 64 + lq * 16) ^ ((lr & 7) << 4)));
        #pragma unroll
        for (int j = 0; j < 2; ++j) {
            const int nt = w * 2 + j;
            acc[j] = MFMA16(Aa, *(const bf16x8*)(Win2p + ((size_t)(kt * 8 + nt) * 64 + l) * 8), acc[j]);
        }
    }
    __syncthreads();   // all M2 reads done before overwrite with n2 tile
    #pragma unroll
    for (int j = 0; j < 2; ++j) {
        const int nt = w * 2 + j, col = nt * 16 + lr;
        #pragma unroll
        for (int i = 0; i < 4; ++i) {
            const int row = lq * 4 + i;
            const float v = fmaxf(acc[j][i] + gproj_n[(size_t)ngv[i] * 128 + col], 0.f);
            *(unsigned short*)(M2 + row * 256 + ((col * 2) ^ ((row & 7) << 4))) = f2bf(v);
        }
    }
    __syncthreads();
    {
        const int flat = tid * 16;
        const int row = flat >> 8, colb = flat & 255;
        bf16x8 v = *(const bf16x8*)(M2 + row * 256 + (colb ^ ((row & 7) << 4)));
        *(bf16x8*)(n2g + (size_t)(n0 + row) * 128 + (colb >> 1)) = v;
    }
}

// -------------------------------------------------------------- global block
extern "C" __global__ void __launch_bounds__(512)
k_global(const float* __restrict__ global_feats,
         const float* __restrict__ Ugn, const float* __restrict__ Uge,
         const float* __restrict__ Ugg, const float* __restrict__ bg,
         const float* __restrict__ Wm, const float* __restrict__ bm,
         const float* __restrict__ Ws, const float* __restrict__ bs,
         const unsigned short* __restrict__ n2g,
         const unsigned short* __restrict__ e2g,
         const int* __restrict__ offN, const int* __restrict__ offE,
         float* __restrict__ out)
{
    __shared__ float redn[32][128], rede[32][128];
    __shared__ float mn[128], me[128], gs[256];
    const int b = blockIdx.x, tid = threadIdx.x;
    const int c = tid & 15, rp = tid >> 4;
    float sn[8] = {0.f, 0.f, 0.f, 0.f, 0.f, 0.f, 0.f, 0.f};
    float se[8] = {0.f, 0.f, 0.f, 0.f, 0.f, 0.f, 0.f, 0.f};
    const int nb = offN[b], ne = offN[b + 1];
    for (int r = nb + rp; r < ne; r += 32) {
        bf16x8 v = *(const bf16x8*)(n2g + (size_t)r * 128 + c * 8);
        #pragma unroll
        for (int j = 0; j < 8; ++j) sn[j] += bfs((unsigned short)v[j]);
    }
    const int eb = offE[b], ee = offE[b + 1];
    for (int r = eb + rp; r < ee; r += 32) {
        bf16x8 v = *(const bf16x8*)(e2g + (size_t)r * 128 + c * 8);
        #pragma unroll
        for (int j = 0; j < 8; ++j) se[j] += bfs((unsigned short)v[j]);
    }
    #pragma unroll
    for (int j = 0; j < 8; ++j) { redn[rp][c * 8 + j] = sn[j]; rede[rp][c * 8 + j] = se[j]; }
    __syncthreads();
    if (tid < 128) {
        float s = 0.f;
        #pragma unroll
        for (int k = 0; k < 32; ++k) s += redn[k][tid];
        mn[tid] = s / fmaxf((float)(ne - nb), 1.0f);
    } else if (tid < 256) {
        const int t = tid - 128;
        float s = 0.f;
        #pragma unroll
        for (int k = 0; k < 32; ++k) s += rede[k][t];
        me[t] = s / fmaxf((float)(ee - eb), 1.0f);
    }
    __syncthreads();

    if (tid < 256) {
        const int h = tid;
        float u = bg[h];
        for (int k = 0; k < 128; ++k) u = fmaf(mn[k], Ugn[k * 256 + h], u);
        for (int k = 0; k < 128; ++k) u = fmaf(me[k], Uge[k * 256 + h], u);
        #pragma unroll
        for (int j = 0; j < GF; ++j) u = fmaf(global_feats[b * GF + j], Ugg[j * 256 + h], u);
        gs[h] = fmaxf(u, 0.0f);
    }
    __syncthreads();

    if (tid < 16) {
        const int a = tid & 7;
        const int which = tid >> 3;
        const float* W = which ? Ws : Wm;
        float acc = which ? bs[a] : bm[a];
        for (int k = 0; k < 256; ++k) acc = fmaf(gs[k], W[k * 8 + a], acc);
        if (which) acc = fminf(fmaxf(acc, -20.0f), 2.0f);
        out[which * 2048 + b * 8 + a] = acc;
    }
}

extern "C" void kernel_launch(void* const* d_in, const int* in_sizes, int n_in,
                              void* d_out, int out_size, void* d_ws, size_t ws_size,
                              hipStream_t stream)
{
    (void)in_sizes; (void)n_in; (void)out_size; (void)ws_size;
    const float* node_feats   = (const float*)d_in[0];
    const float* edge_feats   = (const float*)d_in[1];
    const float* global_feats = (const float*)d_in[2];
    const int*   receivers    = (const int*)d_in[3];
    const int*   node_graph   = (const int*)d_in[4];
    const int*   edge_graph   = (const int*)d_in[5];
    const float* We1 = (const float*)d_in[6];
    const float* be1 = (const float*)d_in[7];
    const float* Wn1 = (const float*)d_in[8];
    const float* Win1= (const float*)d_in[9];
    const float* bn1 = (const float*)d_in[10];
    const float* We2 = (const float*)d_in[11];
    const float* Weg2= (const float*)d_in[12];
    const float* be2 = (const float*)d_in[13];
    const float* Wn2 = (const float*)d_in[14];
    const float* Win2= (const float*)d_in[15];
    const float* Wng2= (const float*)d_in[16];
    const float* bn2 = (const float*)d_in[17];
    const float* Ugn = (const float*)d_in[18];
    const float* Uge = (const float*)d_in[19];
    const float* Ugg = (const float*)d_in[20];
    const float* bg  = (const float*)d_in[21];
    const float* Wm  = (const float*)d_in[22];
    const float* bm  = (const float*)d_in[23];
    const float* Ws  = (const float*)d_in[24];
    const float* bs  = (const float*)d_in[25];

    char* p = (char*)d_ws;
    auto alloc = [&](size_t bytes) -> char* {
        char* r = p; p += (bytes + 255) & ~(size_t)255; return r;
    };
    // zeroed region
    int* cntR  = (int*)alloc(16384 * 4);
    int* curR  = (int*)alloc(16384 * 4);
    const size_t zero_bytes = (size_t)(p - (char*)d_ws);
    // overwritten-every-call region
    int* offR = (int*)alloc(16385 * 4);
    int* bsum = (int*)alloc(16 * 4);
    int* offN = (int*)alloc(257 * 4);
    int* offE = (int*)alloc(257 * 4);
    int* perm = (int*)alloc((size_t)N_EDGES * 4);
    float* gproj_e = (float*)alloc((size_t)BGR * 128 * 4);
    float* gproj_n = (float*)alloc((size_t)BGR * 128 * 4);
    unsigned short* We1p  = (unsigned short*)alloc((size_t)32 * 256 * 2);
    unsigned short* We2p  = (unsigned short*)alloc((size_t)256 * 128 * 2);
    unsigned short* Wn1p  = (unsigned short*)alloc((size_t)64 * 256 * 2);
    unsigned short* Win1p = (unsigned short*)alloc((size_t)256 * 256 * 2);
    unsigned short* Wn2p  = (unsigned short*)alloc((size_t)256 * 128 * 2);
    unsigned short* Win2p = (unsigned short*)alloc((size_t)128 * 128 * 2);
    unsigned short* mean1g = (unsigned short*)alloc((size_t)N_NODES * 256 * 2);
    unsigned short* mean2g = (unsigned short*)alloc((size_t)N_NODES * 128 * 2);
    float* pfirst1 = (float*)alloc((size_t)(N_EDGES / 64) * 256 * 4);
    float* plast1  = (float*)alloc((size_t)(N_EDGES / 64) * 256 * 4);
    float* pfirst2 = (float*)alloc((size_t)(N_EDGES / 64) * 128 * 4);
    float* plast2  = (float*)alloc((size_t)(N_EDGES / 64) * 128 * 4);
    unsigned short* e2g = (unsigned short*)alloc((size_t)N_EDGES * 128 * 2);
    unsigned short* n2g = (unsigned short*)alloc((size_t)N_NODES * 128 * 2);

    hipMemsetAsync(d_ws, 0, zero_bytes, stream);

    k_prep<<<726, 256, 0, stream>>>(
        We1, We2, Wn1, Win1, Wn2, Win2,
        We1p, We2p, Wn1p, Win1p, Wn2p, Win2p,
        global_feats, Weg2, be2, Wng2, bn2, gproj_e, gproj_n,
        receivers, cntR, node_graph, edge_graph, offN, offE);
    k_scanA<<<16, 256, 0, stream>>>(cntR, offR, bsum);
    k_scanB<<<65, 256, 0, stream>>>(offR, bsum);
    k_scatter<<<N_EDGES / 256, 256, 0, stream>>>(receivers, offR, curR, perm);
    k_edge<<<N_EDGES / 64, 256, 0, stream>>>(
        edge_feats, perm, receivers, edge_graph, We1p, We2p, be1, gproj_e,
        offR, mean1g, mean2g, pfirst1, plast1, pfirst2, plast2, e2g);
    k_nodeagg<<<N_NODES / 16, 256, 0, stream>>>(
        node_feats, node_graph, offR, mean1g, mean2g,
        pfirst1, plast1, pfirst2, plast2,
        Wn1p, Win1p, Wn2p, Win2p, bn1, gproj_n, n2g);
    k_global<<<BGR, 512, 0, stream>>>(
        global_feats, Ugn, Uge, Ugg, bg, Wm, bm, Ws, bs,
        n2g, e2g, offN, offE, (float*)d_out);
}

// Round 14
// 116.141 us; speedup vs baseline: 1.7371x; 1.7371x over previous
//
#include <hip/hip_runtime.h>
#include <cstddef>

#define N_NODES 16384
#define N_EDGES 131072
#define BGR 256
#define NF 64
#define EF 32
#define GF 16

typedef __attribute__((ext_vector_type(8))) short bf16x8;
typedef __attribute__((ext_vector_type(4))) float f32x4;

#define MFMA16(a, b, c) __builtin_amdgcn_mfma_f32_16x16x32_bf16((a), (b), (c), 0, 0, 0)
__device__ const f32x4 ZERO4 = {0.f, 0.f, 0.f, 0.f};

__device__ inline unsigned short f2bf(float f) {
    return (unsigned short)((__builtin_bit_cast(unsigned, f) + 0x8000u) >> 16);
}
__device__ inline float bfs(unsigned short x) {
    return __builtin_bit_cast(float, (unsigned)x << 16);
}

__device__ inline bf16x8 pack8(float4 f0, float4 f1) {
    bf16x8 a;
    a[0] = (short)f2bf(f0.x); a[1] = (short)f2bf(f0.y);
    a[2] = (short)f2bf(f0.z); a[3] = (short)f2bf(f0.w);
    a[4] = (short)f2bf(f1.x); a[5] = (short)f2bf(f1.y);
    a[6] = (short)f2bf(f1.z); a[7] = (short)f2bf(f1.w);
    return a;
}

// --------------------------------------------------------------------- prep
extern "C" __global__ void __launch_bounds__(256)
k_prep(const float* __restrict__ We1, const float* __restrict__ We2,
       const float* __restrict__ Wn1, const float* __restrict__ Win1,
       const float* __restrict__ Wn2, const float* __restrict__ Win2,
       unsigned short* We1p, unsigned short* We2p, unsigned short* Wn1p,
       unsigned short* Win1p, unsigned short* Wn2p, unsigned short* Win2p,
       const float* __restrict__ gf,
       const float* __restrict__ Weg2, const float* __restrict__ be2,
       const float* __restrict__ Wng2, const float* __restrict__ bn2,
       float* __restrict__ gproj_e, float* __restrict__ gproj_n,
       const int* __restrict__ receivers, int* cntR,
       const int* __restrict__ node_graph, const int* __restrict__ edge_graph,
       int* offN, int* offE)
{
    const int bid = blockIdx.x, tid = threadIdx.x;
    if (bid < 84) {
        const int fi = bid * 4 + (tid >> 6), l = tid & 63;
        const float* W; unsigned short* P; int N, t;
        if      (fi < 16)  { W = We1;  P = We1p;  N = 256; t = fi;       }
        else if (fi < 80)  { W = We2;  P = We2p;  N = 128; t = fi - 16;  }
        else if (fi < 112) { W = Wn1;  P = Wn1p;  N = 256; t = fi - 80;  }
        else if (fi < 240) { W = Win1; P = Win1p; N = 256; t = fi - 112; }
        else if (fi < 304) { W = Wn2;  P = Wn2p;  N = 128; t = fi - 240; }
        else               { W = Win2; P = Win2p; N = 128; t = fi - 304; }
        const int NT = N / 16;
        const int kt = t / NT, nt = t % NT;
        const int k0 = kt * 32 + (l >> 4) * 8;
        const int col = nt * 16 + (l & 15);
        unsigned short* dst = P + ((size_t)t * 64 + l) * 8;
        #pragma unroll
        for (int j = 0; j < 8; ++j) dst[j] = f2bf(W[(size_t)(k0 + j) * N + col]);
    } else if (bid < 212) {
        const int b = (bid - 84) * 2 + (tid >> 7), t = tid & 127;
        float ge = be2[t], gn = bn2[t];
        #pragma unroll
        for (int j = 0; j < GF; ++j) {
            const float g = gf[b * GF + j];
            ge = fmaf(g, Weg2[j * 128 + t], ge);
            gn = fmaf(g, Wng2[j * 128 + t], gn);
        }
        gproj_e[b * 128 + t] = ge;
        gproj_n[b * 128 + t] = gn;
    } else if (bid < 724) {
        const int i = (bid - 212) * 256 + tid;
        atomicAdd(&cntR[receivers[i]], 1);
    } else {
        const int g = tid;
        const int* arr = (bid == 725) ? edge_graph : node_graph;
        int* dst       = (bid == 725) ? offE       : offN;
        const int len  = (bid == 725) ? N_EDGES    : N_NODES;
        int lo = 0, hi = len;
        while (lo < hi) {
            const int mid = (lo + hi) >> 1;
            if (arr[mid] < g) lo = mid + 1; else hi = mid;
        }
        dst[g] = lo;
        if (g == 0) dst[256] = len;
    }
}

// ---------------------------------------------------------- parallel scan
extern "C" __global__ void __launch_bounds__(256)
k_scanA(const int* __restrict__ cntR, int* __restrict__ offR, int* __restrict__ bsum)
{
    __shared__ int sm[256];
    const int b = blockIdx.x, t = threadIdx.x;
    const int4 v = *(const int4*)(cntR + b * 1024 + t * 4);
    const int s = v.x + v.y + v.z + v.w;
    sm[t] = s; __syncthreads();
    for (int o = 1; o < 256; o <<= 1) {
        int x = (t >= o) ? sm[t - o] : 0;
        __syncthreads(); sm[t] += x; __syncthreads();
    }
    const int excl = sm[t] - s;
    int4 o;
    o.x = excl; o.y = excl + v.x; o.z = o.y + v.y; o.w = o.z + v.z;
    *(int4*)(offR + b * 1024 + t * 4) = o;
    if (t == 255) bsum[b] = sm[255];
}

extern "C" __global__ void __launch_bounds__(256)
k_scanB(int* __restrict__ offR, const int* __restrict__ bsum)
{
    const int i = blockIdx.x * 256 + threadIdx.x;
    if (i > 16384) return;
    const int g = i >> 10;
    int pre = 0;
    for (int k = 0; k < g; ++k) pre += bsum[k];
    offR[i] = (i < 16384 ? offR[i] : 0) + pre;
}

extern "C" __global__ void __launch_bounds__(256)
k_scatter(const int* __restrict__ receivers, const int* __restrict__ offR,
          int* curR, int* perm)
{
    const int i = blockIdx.x * 256 + threadIdx.x;
    if (i < N_EDGES) {
        const int r = receivers[i];
        const int pos = offR[r] + atomicAdd(&curR[r], 1);
        perm[pos] = i;
    }
}

// ---------------------------------------------------------------- edge block
// PERM (receiver-sorted) order, 64 edges/block, 4 waves tiling N.
// e1 -> e1p (perm-contig, for k_nodeagg's contiguous stream);
// e2 -> e2g (ORIGINAL order, for k_global's contiguous graph ranges).
extern "C" __global__ void __launch_bounds__(256)
k_edge(const float* __restrict__ edge_feats,
       const int* __restrict__ perm,
       const int* __restrict__ edge_graph,
       const unsigned short* __restrict__ We1p,
       const unsigned short* __restrict__ We2p,
       const float* __restrict__ be1,
       const float* __restrict__ gproj_e,
       unsigned short* __restrict__ e1p,
       unsigned short* __restrict__ e2g)
{
    __shared__ __align__(16) unsigned short e1s[64 * 256];   // 32 KB, swizzled
    const int tid = threadIdx.x;
    const int w = tid >> 6, l = tid & 63;
    const int lr = l & 15, lq = l >> 4;
    const int e0 = blockIdx.x * 64;
    char* B = (char*)e1s;

    int eidA[4];
    int egC[4][4];
    #pragma unroll
    for (int g = 0; g < 4; ++g) eidA[g] = perm[e0 + g * 16 + lr];
    #pragma unroll
    for (int g = 0; g < 4; ++g)
        #pragma unroll
        for (int i = 0; i < 4; ++i)
            egC[g][i] = edge_graph[perm[e0 + g * 16 + lq * 4 + i]];

    // ---- e1: M=64 (4 row-groups, A shared), wave owns nt = w*4..w*4+3 ----
    bf16x8 a[4];
    #pragma unroll
    for (int g = 0; g < 4; ++g) {
        const float* s = edge_feats + (size_t)eidA[g] * EF + lq * 8;
        a[g] = pack8(*(const float4*)s, *(const float4*)(s + 4));
    }
    #pragma unroll
    for (int j = 0; j < 4; ++j) {
        const int nt = w * 4 + j;
        bf16x8 bfr = *(const bf16x8*)(We1p + ((size_t)nt * 64 + l) * 8);
        const int col = nt * 16 + lr;
        const float bias = be1[col];
        #pragma unroll
        for (int g = 0; g < 4; ++g) {
            f32x4 c = MFMA16(a[g], bfr, ZERO4);
            #pragma unroll
            for (int i = 0; i < 4; ++i) {
                const int row = g * 16 + lq * 4 + i;
                const float v = fmaxf(c[i] + bias, 0.f);
                *(unsigned short*)(B + row * 512 + ((col * 2) ^ ((row & 7) << 4))) = f2bf(v);
            }
        }
    }
    __syncthreads();

    // ---- dump e1 -> e1p (perm-contiguous), 16B/lane ----
    #pragma unroll
    for (int it = 0; it < 8; ++it) {
        const int flat = it * 4096 + tid * 16;
        const int row = flat >> 9, colb = flat & 511;
        bf16x8 v = *(const bf16x8*)(B + row * 512 + (colb ^ ((row & 7) << 4)));
        *(bf16x8*)(e1p + (size_t)(e0 + row) * 256 + (colb >> 1)) = v;
    }

    // ---- e2: K=256 from LDS (all rows), wave owns nt = w*2, w*2+1 ----
    f32x4 acc[4][2];
    #pragma unroll
    for (int g = 0; g < 4; ++g) {
        acc[g][0] = ZERO4;
        acc[g][1] = ZERO4;
    }
    #pragma unroll
    for (int kt = 0; kt < 8; ++kt) {
        bf16x8 pA[4];
        #pragma unroll
        for (int g = 0; g < 4; ++g) {
            const int row = g * 16 + lr;
            pA[g] = *(const bf16x8*)(B + row * 512 + ((kt * 64 + lq * 16) ^ ((lr & 7) << 4)));
        }
        #pragma unroll
        for (int j = 0; j < 2; ++j) {
            const int nt = w * 2 + j;
            bf16x8 bfr = *(const bf16x8*)(We2p + ((size_t)(kt * 8 + nt) * 64 + l) * 8);
            #pragma unroll
            for (int g = 0; g < 4; ++g) acc[g][j] = MFMA16(pA[g], bfr, acc[g][j]);
        }
    }
    __syncthreads();   // all LDS reads done before overwrite

    #pragma unroll
    for (int j = 0; j < 2; ++j) {
        const int nt = w * 2 + j, col = nt * 16 + lr;
        #pragma unroll
        for (int g = 0; g < 4; ++g)
            #pragma unroll
            for (int i = 0; i < 4; ++i) {
                const int row = g * 16 + lq * 4 + i;
                const float v = fmaxf(acc[g][j][i] + gproj_e[(size_t)egC[g][i] * 128 + col], 0.f);
                *(unsigned short*)(B + row * 512 + ((col * 2) ^ ((row & 7) << 4))) = f2bf(v);
            }
    }
    __syncthreads();
    #pragma unroll
    for (int it = 0; it < 4; ++it) {
        const int flat = it * 4096 + tid * 16;
        const int row = flat >> 8, colb = flat & 255;
        bf16x8 v = *(const bf16x8*)(B + row * 512 + (colb ^ ((row & 7) << 4)));
        const int eid = perm[e0 + row];
        *(bf16x8*)(e2g + (size_t)eid * 128 + (colb >> 1)) = v;
    }
}

// -------------------------------------------- fused aggregate + node block
// 16 nodes/block (1024 blocks), 4 waves. Phase A: stream e1p (perm-contig)
// + gather e2g via perm -> per-node means in LDS. Phases B/C: n1, n2 GEMMs.
extern "C" __global__ void __launch_bounds__(256)
k_nodeagg(const float* __restrict__ node_feats,
          const int* __restrict__ node_graph,
          const int* __restrict__ offR,
          const int* __restrict__ perm,
          const unsigned short* __restrict__ e1p,
          const unsigned short* __restrict__ e2g,
          const unsigned short* __restrict__ Wn1p,
          const unsigned short* __restrict__ Win1p,
          const unsigned short* __restrict__ Wn2p,
          const unsigned short* __restrict__ Win2p,
          const float* __restrict__ bn1,
          const float* __restrict__ gproj_n,
          unsigned short* __restrict__ n2g)
{
    __shared__ __align__(16) unsigned short m1s[16 * 256];   // 8 KB  mean1
    __shared__ __align__(16) unsigned short m2s[16 * 128];   // 4 KB  mean2 / n2
    __shared__ __align__(16) unsigned short n1s[16 * 256];   // 8 KB  n1
    const int tid = threadIdx.x;
    const int w = tid >> 6, l = tid & 63;
    const int lr = l & 15, lq = l >> 4;
    const int n0 = blockIdx.x * 16;
    char* M1 = (char*)m1s; char* M2 = (char*)m2s; char* N1 = (char*)n1s;

    // ---- phase A: aggregate; wave w handles nodes w*4..w*4+3 ----
    const int half = l >> 5, li = l & 31, q = l >> 4;
    for (int jn = 0; jn < 4; ++jn) {
        const int rn = w * 4 + jn, n = n0 + rn;
        const int c0 = offR[n], c1 = offR[n + 1];
        float s1[8] = {0.f, 0.f, 0.f, 0.f, 0.f, 0.f, 0.f, 0.f};
        float s2[8] = {0.f, 0.f, 0.f, 0.f, 0.f, 0.f, 0.f, 0.f};
        int r = c0;
        for (; r + 2 <= c1; r += 2) {                 // e1p: 2 rows (512B) /iter
            bf16x8 v = *(const bf16x8*)(e1p + (size_t)(r + half) * 256 + li * 8);
            #pragma unroll
            for (int j = 0; j < 8; ++j) s1[j] += bfs((unsigned short)v[j]);
        }
        if (r < c1 && half == 0) {
            bf16x8 v = *(const bf16x8*)(e1p + (size_t)r * 256 + li * 8);
            #pragma unroll
            for (int j = 0; j < 8; ++j) s1[j] += bfs((unsigned short)v[j]);
        }
        r = c0;
        for (; r + 4 <= c1; r += 4) {                 // e2g: 4 rows via perm
            const int eid = perm[r + q];
            bf16x8 v = *(const bf16x8*)(e2g + (size_t)eid * 128 + lr * 8);
            #pragma unroll
            for (int j = 0; j < 8; ++j) s2[j] += bfs((unsigned short)v[j]);
        }
        if (r + q < c1) {
            const int eid = perm[r + q];
            bf16x8 v = *(const bf16x8*)(e2g + (size_t)eid * 128 + lr * 8);
            #pragma unroll
            for (int j = 0; j < 8; ++j) s2[j] += bfs((unsigned short)v[j]);
        }
        #pragma unroll
        for (int j = 0; j < 8; ++j) s1[j] += __shfl_xor(s1[j], 32);
        #pragma unroll
        for (int j = 0; j < 8; ++j) {
            s2[j] += __shfl_xor(s2[j], 16);
            s2[j] += __shfl_xor(s2[j], 32);
        }
        const float inv = 1.0f / fmaxf((float)(c1 - c0), 1.0f);
        if (half == 0) {
            bf16x8 o;
            #pragma unroll
            for (int j = 0; j < 8; ++j) o[j] = (short)f2bf(s1[j] * inv);
            *(bf16x8*)(M1 + rn * 512 + ((li * 16) ^ ((rn & 7) << 4))) = o;
        }
        if (l < 16) {
            bf16x8 o;
            #pragma unroll
            for (int j = 0; j < 8; ++j) o[j] = (short)f2bf(s2[j] * inv);
            *(bf16x8*)(M2 + rn * 256 + ((l * 16) ^ ((rn & 7) << 4))) = o;
        }
    }
    __syncthreads();

    // ---- phase B: n1 (M=16, K=64+256), wave owns nt = w*4..w*4+3 ----
    bf16x8 A1[10];
    #pragma unroll
    for (int kt = 0; kt < 2; ++kt) {
        const float* s = node_feats + (size_t)(n0 + lr) * NF + kt * 32 + lq * 8;
        A1[kt] = pack8(*(const float4*)s, *(const float4*)(s + 4));
    }
    #pragma unroll
    for (int kt = 0; kt < 8; ++kt)
        A1[2 + kt] = *(const bf16x8*)(M1 + lr * 512 + ((kt * 64 + lq * 16) ^ ((lr & 7) << 4)));
    #pragma unroll
    for (int j = 0; j < 4; ++j) {
        const int nt = w * 4 + j, col = nt * 16 + lr;
        f32x4 c = ZERO4;
        #pragma unroll
        for (int kt = 0; kt < 2; ++kt)
            c = MFMA16(A1[kt], *(const bf16x8*)(Wn1p + ((size_t)(kt * 16 + nt) * 64 + l) * 8), c);
        #pragma unroll
        for (int kt = 0; kt < 8; ++kt)
            c = MFMA16(A1[2 + kt], *(const bf16x8*)(Win1p + ((size_t)(kt * 16 + nt) * 64 + l) * 8), c);
        const float bias = bn1[col];
        #pragma unroll
        for (int i = 0; i < 4; ++i) {
            const int row = lq * 4 + i;
            const float v = fmaxf(c[i] + bias, 0.f);
            *(unsigned short*)(N1 + row * 512 + ((col * 2) ^ ((row & 7) << 4))) = f2bf(v);
        }
    }
    __syncthreads();

    // ---- phase C: n2 (M=16, K=256+128), wave owns nt = w*2, w*2+1 ----
    int ngv[4];
    #pragma unroll
    for (int i = 0; i < 4; ++i) ngv[i] = node_graph[n0 + lq * 4 + i];
    f32x4 acc[2];
    acc[0] = ZERO4;
    acc[1] = ZERO4;
    #pragma unroll
    for (int kt = 0; kt < 8; ++kt) {
        bf16x8 Aa = *(const bf16x8*)(N1 + lr * 512 + ((kt * 64 + lq * 16) ^ ((lr & 7) << 4)));
        #pragma unroll
        for (int j = 0; j < 2; ++j) {
            const int nt = w * 2 + j;
            acc[j] = MFMA16(Aa, *(const bf16x8*)(Wn2p + ((size_t)(kt * 8 + nt) * 64 + l) * 8), acc[j]);
        }
    }
    #pragma unroll
    for (int kt = 0; kt < 4; ++kt) {
        bf16x8 Aa = *(const bf16x8*)(M2 + lr * 256 + ((kt * 64 + lq * 16) ^ ((lr & 7) << 4)));
        #pragma unroll
        for (int j = 0; j < 2; ++j) {
            const int nt = w * 2 + j;
            acc[j] = MFMA16(Aa, *(const bf16x8*)(Win2p + ((size_t)(kt * 8 + nt) * 64 + l) * 8), acc[j]);
        }
    }
    __syncthreads();   // all M2 reads done before overwrite with n2 tile
    #pragma unroll
    for (int j = 0; j < 2; ++j) {
        const int nt = w * 2 + j, col = nt * 16 + lr;
        #pragma unroll
        for (int i = 0; i < 4; ++i) {
            const int row = lq * 4 + i;
            const float v = fmaxf(acc[j][i] + gproj_n[(size_t)ngv[i] * 128 + col], 0.f);
            *(unsigned short*)(M2 + row * 256 + ((col * 2) ^ ((row & 7) << 4))) = f2bf(v);
        }
    }
    __syncthreads();
    {
        const int flat = tid * 16;                    // 16 rows x 256B = 4 KB
        const int row = flat >> 8, colb = flat & 255;
        bf16x8 v = *(const bf16x8*)(M2 + row * 256 + (colb ^ ((row & 7) << 4)));
        *(bf16x8*)(n2g + (size_t)(n0 + row) * 128 + (colb >> 1)) = v;
    }
}

// -------------------------------------------------------------- global block
extern "C" __global__ void __launch_bounds__(512)
k_global(const float* __restrict__ global_feats,
         const float* __restrict__ Ugn, const float* __restrict__ Uge,
         const float* __restrict__ Ugg, const float* __restrict__ bg,
         const float* __restrict__ Wm, const float* __restrict__ bm,
         const float* __restrict__ Ws, const float* __restrict__ bs,
         const unsigned short* __restrict__ n2g,
         const unsigned short* __restrict__ e2g,
         const int* __restrict__ offN, const int* __restrict__ offE,
         float* __restrict__ out)
{
    __shared__ float redn[32][128], rede[32][128];
    __shared__ float mn[128], me[128], gs[256];
    const int b = blockIdx.x, tid = threadIdx.x;
    const int c = tid & 15, rp = tid >> 4;
    float sn[8] = {0.f, 0.f, 0.f, 0.f, 0.f, 0.f, 0.f, 0.f};
    float se[8] = {0.f, 0.f, 0.f, 0.f, 0.f, 0.f, 0.f, 0.f};
    const int nb = offN[b], ne = offN[b + 1];
    for (int r = nb + rp; r < ne; r += 32) {
        bf16x8 v = *(const bf16x8*)(n2g + (size_t)r * 128 + c * 8);
        #pragma unroll
        for (int j = 0; j < 8; ++j) sn[j] += bfs((unsigned short)v[j]);
    }
    const int eb = offE[b], ee = offE[b + 1];
    for (int r = eb + rp; r < ee; r += 32) {
        bf16x8 v = *(const bf16x8*)(e2g + (size_t)r * 128 + c * 8);
        #pragma unroll
        for (int j = 0; j < 8; ++j) se[j] += bfs((unsigned short)v[j]);
    }
    #pragma unroll
    for (int j = 0; j < 8; ++j) { redn[rp][c * 8 + j] = sn[j]; rede[rp][c * 8 + j] = se[j]; }
    __syncthreads();
    if (tid < 128) {
        float s = 0.f;
        #pragma unroll
        for (int k = 0; k < 32; ++k) s += redn[k][tid];
        mn[tid] = s / fmaxf((float)(ne - nb), 1.0f);
    } else if (tid < 256) {
        const int t = tid - 128;
        float s = 0.f;
        #pragma unroll
        for (int k = 0; k < 32; ++k) s += rede[k][t];
        me[t] = s / fmaxf((float)(ee - eb), 1.0f);
    }
    __syncthreads();

    if (tid < 256) {
        const int h = tid;
        float u = bg[h];
        for (int k = 0; k < 128; ++k) u = fmaf(mn[k], Ugn[k * 256 + h], u);
        for (int k = 0; k < 128; ++k) u = fmaf(me[k], Uge[k * 256 + h], u);
        #pragma unroll
        for (int j = 0; j < GF; ++j) u = fmaf(global_feats[b * GF + j], Ugg[j * 256 + h], u);
        gs[h] = fmaxf(u, 0.0f);
    }
    __syncthreads();

    if (tid < 16) {
        const int a = tid & 7;
        const int which = tid >> 3;
        const float* W = which ? Ws : Wm;
        float acc = which ? bs[a] : bm[a];
        for (int k = 0; k < 256; ++k) acc = fmaf(gs[k], W[k * 8 + a], acc);
        if (which) acc = fminf(fmaxf(acc, -20.0f), 2.0f);
        out[which * 2048 + b * 8 + a] = acc;
    }
}

extern "C" void kernel_launch(void* const* d_in, const int* in_sizes, int n_in,
                              void* d_out, int out_size, void* d_ws, size_t ws_size,
                              hipStream_t stream)
{
    (void)in_sizes; (void)n_in; (void)out_size; (void)ws_size;
    const float* node_feats   = (const float*)d_in[0];
    const float* edge_feats   = (const float*)d_in[1];
    const float* global_feats = (const float*)d_in[2];
    const int*   receivers    = (const int*)d_in[3];
    const int*   node_graph   = (const int*)d_in[4];
    const int*   edge_graph   = (const int*)d_in[5];
    const float* We1 = (const float*)d_in[6];
    const float* be1 = (const float*)d_in[7];
    const float* Wn1 = (const float*)d_in[8];
    const float* Win1= (const float*)d_in[9];
    const float* bn1 = (const float*)d_in[10];
    const float* We2 = (const float*)d_in[11];
    const float* Weg2= (const float*)d_in[12];
    const float* be2 = (const float*)d_in[13];
    const float* Wn2 = (const float*)d_in[14];
    const float* Win2= (const float*)d_in[15];
    const float* Wng2= (const float*)d_in[16];
    const float* bn2 = (const float*)d_in[17];
    const float* Ugn = (const float*)d_in[18];
    const float* Uge = (const float*)d_in[19];
    const float* Ugg = (const float*)d_in[20];
    const float* bg  = (const float*)d_in[21];
    const float* Wm  = (const float*)d_in[22];
    const float* bm  = (const float*)d_in[23];
    const float* Ws  = (const float*)d_in[24];
    const float* bs  = (const float*)d_in[25];

    char* p = (char*)d_ws;
    auto alloc = [&](size_t bytes) -> char* {
        char* r = p; p += (bytes + 255) & ~(size_t)255; return r;
    };
    // zeroed region
    int* cntR  = (int*)alloc(16384 * 4);
    int* curR  = (int*)alloc(16384 * 4);
    const size_t zero_bytes = (size_t)(p - (char*)d_ws);
    // overwritten-every-call region
    int* offR = (int*)alloc(16385 * 4);
    int* bsum = (int*)alloc(16 * 4);
    int* offN = (int*)alloc(257 * 4);
    int* offE = (int*)alloc(257 * 4);
    int* perm = (int*)alloc((size_t)N_EDGES * 4);
    float* gproj_e = (float*)alloc((size_t)BGR * 128 * 4);
    float* gproj_n = (float*)alloc((size_t)BGR * 128 * 4);
    unsigned short* We1p  = (unsigned short*)alloc((size_t)32 * 256 * 2);
    unsigned short* We2p  = (unsigned short*)alloc((size_t)256 * 128 * 2);
    unsigned short* Wn1p  = (unsigned short*)alloc((size_t)64 * 256 * 2);
    unsigned short* Win1p = (unsigned short*)alloc((size_t)256 * 256 * 2);
    unsigned short* Wn2p  = (unsigned short*)alloc((size_t)256 * 128 * 2);
    unsigned short* Win2p = (unsigned short*)alloc((size_t)128 * 128 * 2);
    unsigned short* e1p = (unsigned short*)alloc((size_t)N_EDGES * 256 * 2);
    unsigned short* e2g = (unsigned short*)alloc((size_t)N_EDGES * 128 * 2);
    unsigned short* n2g = (unsigned short*)alloc((size_t)N_NODES * 128 * 2);

    hipMemsetAsync(d_ws, 0, zero_bytes, stream);

    k_prep<<<726, 256, 0, stream>>>(
        We1, We2, Wn1, Win1, Wn2, Win2,
        We1p, We2p, Wn1p, Win1p, Wn2p, Win2p,
        global_feats, Weg2, be2, Wng2, bn2, gproj_e, gproj_n,
        receivers, cntR, node_graph, edge_graph, offN, offE);
    k_scanA<<<16, 256, 0, stream>>>(cntR, offR, bsum);
    k_scanB<<<65, 256, 0, stream>>>(offR, bsum);
    k_scatter<<<N_EDGES / 256, 256, 0, stream>>>(receivers, offR, curR, perm);
    k_edge<<<N_EDGES / 64, 256, 0, stream>>>(
        edge_feats, perm, edge_graph, We1p, We2p, be1, gproj_e, e1p, e2g);
    k_nodeagg<<<N_NODES / 16, 256, 0, stream>>>(
        node_feats, node_graph, offR, perm, e1p, e2g,
        Wn1p, Win1p, Wn2p, Win2p, bn1, gproj_n, n2g);
    k_global<<<BGR, 512, 0, stream>>>(
        global_feats, Ugn, Uge, Ugg, bg, Wm, bm, Ws, bs,
        n2g, e2g, offN, offE, (float*)d_out);
}